// Round 1
// baseline (100.064 us; speedup 1.0000x reference)
//
#include <hip/hip_runtime.h>

// Problem constants: O=256, I=512, K=3, C=128, B=128, T=I=512
#define O_ 256
#define I_ 512
#define K_ 3
#define C_ 128
#define B_ 128
#define T_ 512

// ---------------------------------------------------------------------------
// kA: yT[c][b] = sum_f x[b][f] * E[c][f]      (y = x @ E^T, stored transposed)
// grid = C_ (one block per c), block = 128 threads (one per b)
// E row staged in LDS (coalesced), x rows streamed as float4 per thread.
// ---------------------------------------------------------------------------
__global__ __launch_bounds__(128) void kA(const float* __restrict__ x,
                                          const float* __restrict__ E,
                                          float* __restrict__ yT) {
    __shared__ float4 e4[I_ / 4];               // 512 floats = 2 KB
    const int c   = blockIdx.x;
    const int tid = threadIdx.x;                // 0..127 == b
    e4[tid] = ((const float4*)(E + (size_t)c * I_))[tid];   // coalesced 2KB
    __syncthreads();

    const float4* x4 = (const float4*)(x + (size_t)tid * I_);
    float acc = 0.0f;
#pragma unroll 8
    for (int i = 0; i < I_ / 4; ++i) {
        float4 xv = x4[i];
        float4 ev = e4[i];                      // uniform addr -> LDS broadcast
        acc += xv.x * ev.x + xv.y * ev.y + xv.z * ev.z + xv.w * ev.w;
    }
    yT[c * B_ + tid] = acc;                     // coalesced
}

// ---------------------------------------------------------------------------
// kB: Z2[(o*B + b)*4 + jj] = sum_c CV[(o*4+jj)*C + c] * yT[c*B + b]
// grid = O_*(K_+1) = 1024 (one block per (o,jj) row), block = 128 (one per b)
// CV row staged in LDS; yT reads coalesced across b at each c.
// Z stored [o][b][jj] so kC can fetch all 4 knots with one float4.
// ---------------------------------------------------------------------------
__global__ __launch_bounds__(128) void kB(const float* __restrict__ CV,
                                          const float* __restrict__ yT,
                                          float* __restrict__ Z2) {
    __shared__ float cv[C_];
    const int row = blockIdx.x;                 // o*4 + jj
    const int b   = threadIdx.x;
    cv[b] = CV[row * C_ + b];                   // coalesced 512B
    __syncthreads();

    float acc = 0.0f;
#pragma unroll 8
    for (int c = 0; c < C_; ++c)
        acc += cv[c] * yT[c * B_ + b];          // cv broadcast, yT coalesced

    const int o  = row >> 2;
    const int jj = row & 3;
    Z2[((o * B_ + b) << 2) + jj] = acc;
}

// ---------------------------------------------------------------------------
// kC: out[(o*B + b)*T + t] = dot(w4[t], Z2row[o*B+b])
// where w4[t] has (1-tl) at knot j[t] and tl at j[t]+1, zeros elsewhere.
// grid = 2048 blocks * 256 threads; each block writes 16 rows (2 per pass).
// Per thread: weight float4s computed ONCE, then per row:
//   1 uniform float4 load + 16 FMA + 1 coalesced float4 store.
// ---------------------------------------------------------------------------
__global__ __launch_bounds__(256) void kC(const float* __restrict__ Z2,
                                          float* __restrict__ out) {
    const int tid = threadIdx.x;
    const int pos = tid & 127;                  // which float4 within the 512-row
    const int rh  = tid >> 7;                   // 0/1: which of 2 rows this pass

    // Per-thread lerp weights for its 4 consecutive t values (computed once).
    float4 w[4];
#pragma unroll
    for (int u = 0; u < 4; ++u) {
        const int   t  = pos * 4 + u;
        const float ts = (float)t * (3.0f / 511.0f);   // t/(I-1) * K
        int j = (int)ts;                               // floor (ts >= 0)
        if (j > K_ - 1) j = K_ - 1;                    // clip to [0, K-1]
        const float tl = ts - (float)j;
        const float om = 1.0f - tl;
        float4 wu;
        wu.x = (j == 0) ? om : 0.0f;
        wu.y = (j == 0) ? tl : ((j == 1) ? om : 0.0f);
        wu.z = (j == 1) ? tl : ((j == 2) ? om : 0.0f);
        wu.w = (j == 2) ? tl : 0.0f;
        w[u] = wu;
    }

    const float4* Z4   = (const float4*)Z2;
    float4*       out4 = (float4*)out;
    const int rbase = blockIdx.x * 16 + rh;

#pragma unroll
    for (int it = 0; it < 8; ++it) {
        const int r = rbase + it * 2;           // row = o*B + b, in [0, 32768)
        const float4 z = Z4[r];                 // uniform per row -> one line
        float4 o4;
        o4.x = w[0].x * z.x + w[0].y * z.y + w[0].z * z.z + w[0].w * z.w;
        o4.y = w[1].x * z.x + w[1].y * z.y + w[1].z * z.z + w[1].w * z.w;
        o4.z = w[2].x * z.x + w[2].y * z.y + w[2].z * z.z + w[2].w * z.w;
        o4.w = w[3].x * z.x + w[3].y * z.y + w[3].z * z.z + w[3].w * z.w;
        out4[(size_t)r * (T_ / 4) + pos] = o4;  // coalesced 2KB per row
    }
}

// ---------------------------------------------------------------------------
// Inputs (setup_inputs order):
//   d_in[0] = x                (B, I)        f32
//   d_in[1] = control_points   (O, K+1)      f32   -- values unused (only k)
//   d_in[2] = control_values   (O, K+1, C)   f32
//   d_in[3] = expansion_matrix (C, I)        f32
// Output: (O, B, T) f32, flat (o*B + b)*T + t
// Workspace: yT 64 KB @ 0, Z2 512 KB @ 65536  (576 KB total)
// ---------------------------------------------------------------------------
extern "C" void kernel_launch(void* const* d_in, const int* in_sizes, int n_in,
                              void* d_out, int out_size, void* d_ws, size_t ws_size,
                              hipStream_t stream) {
    const float* x  = (const float*)d_in[0];
    const float* CV = (const float*)d_in[2];
    const float* E  = (const float*)d_in[3];
    float* out = (float*)d_out;

    float* yT = (float*)d_ws;                         // C_*B_*4   = 64 KB
    float* Z2 = (float*)((char*)d_ws + 65536);        // O_*4*B_*4 = 512 KB

    kA<<<C_, 128, 0, stream>>>(x, E, yT);
    kB<<<O_ * (K_ + 1), 128, 0, stream>>>(CV, yT, Z2);
    kC<<<(O_ * B_) / 16, 256, 0, stream>>>(Z2, out);
}